// Round 6
// baseline (92.148 us; speedup 1.0000x reference)
//
#include <hip/hip_runtime.h>
#include <math.h>

#define IMG 256
#define NA  360
#define ND  363
#define NB  2                  // B*C image count
#define KMAX 181               // (ND-1)/2
#define ST  544                // padded row stride for filtered sinogram
#define PAD 76                 // left zero-pad (min u = 181 - 181.7*sqrt(2) > -76)
#define HT_N 736               // 725 used taps + alignment/over-read padding

// ---------------------------------------------------------------------------
// Kernel 0 (one-shot, ~1 us): extended ramp-filter tap table to GLOBAL.
//   ht[i] = h(i-362), i in [0,725);  h(n) = S(2*pi*n/ND) * 4/ND^2
//   S(w) = ((K+1)cos(Kw) - K*cos((K+1)w) - 1) / (2*(1-cos w)),  S(0)=K(K+1)/2
// Entries 725..735 are zero padding (only over-read, never used in a product
// that is stored). Previously every conv block rebuilt this table (720x).
// ---------------------------------------------------------------------------
__global__ void fbp_ht(float* __restrict__ ht) {
    int i = blockIdx.x * 368 + threadIdx.x;
    if (i >= HT_N) return;
    float v = 0.f;
    if (i <= 724) {
        int n = i - 362;
        double S;
        if (n == 0) {
            S = (double)KMAX * (double)(KMAX + 1) * 0.5;
        } else {
            double w = (2.0 * M_PI / (double)ND) * (double)n;
            S = ((double)(KMAX + 1) * cos((double)KMAX * w)
               - (double)KMAX * cos((double)(KMAX + 1) * w) - 1.0)
              / (2.0 * (1.0 - cos(w)));
        }
        v = (float)(S * (4.0 / ((double)ND * (double)ND)));
    }
    ht[i] = v;
}

// ---------------------------------------------------------------------------
// Kernel 1: ramp convolution, output-blocked P=4 with sliding tap window.
// One row per 128-thread block; thread t computes outputs d0=4t..4t+3
// (t<91 active). Per 8-m chunk: taps ht[d0+8c .. d0+8c+10] = 3 coalesced
// aligned float4 global loads (lane t -> ht4[t+2c], 16B/lane, L1-hot) for
// 32 FMAs. Sinogram taps srow[m] are wave-uniform -> scalar loads.
// VALU-bound: ~46*32*2 cyc/wave ~= 2 us across the grid. No LDS at all.
// ---------------------------------------------------------------------------
__global__ __launch_bounds__(128) void fbp_conv(const float* __restrict__ sino,
                                                const float* __restrict__ htg,
                                                float* __restrict__ filt) {
    const int row = blockIdx.x;
    const int t = threadIdx.x;
    const float* __restrict__ srow = sino + (size_t)row * ND;
    float* __restrict__ orow = filt + (size_t)row * ST;
    const float4* __restrict__ ht4 = (const float4*)htg;

    if (t < 91) {
        float acc0 = 0.f, acc1 = 0.f, acc2 = 0.f, acc3 = 0.f;

#pragma unroll 2
        for (int c = 0; c < 45; ++c) {
            float4 A = ht4[t + 2 * c];
            float4 B = ht4[t + 2 * c + 1];
            float4 C = ht4[t + 2 * c + 2];
            const float W[12] = {A.x, A.y, A.z, A.w, B.x, B.y, B.z, B.w,
                                 C.x, C.y, C.z, C.w};
            const int m0 = 362 - 8 * c;
#pragma unroll
            for (int j = 0; j < 8; ++j) {
                float s = srow[m0 - j];              // wave-uniform scalar
                acc0 = fmaf(s, W[j + 0], acc0);
                acc1 = fmaf(s, W[j + 1], acc1);
                acc2 = fmaf(s, W[j + 2], acc2);
                acc3 = fmaf(s, W[j + 3], acc3);
            }
        }
        // tail: m = 2,1,0  (window base x = d0+360 -> float4 index t+90)
        {
            float4 A = ht4[t + 90];
            float4 B = ht4[t + 91];
            const float W[8] = {A.x, A.y, A.z, A.w, B.x, B.y, B.z, B.w};
#pragma unroll
            for (int j = 0; j < 3; ++j) {
                float s = srow[2 - j];
                acc0 = fmaf(s, W[j + 0], acc0);
                acc1 = fmaf(s, W[j + 1], acc1);
                acc2 = fmaf(s, W[j + 2], acc2);
                acc3 = fmaf(s, W[j + 3], acc3);
            }
        }
        const int d0 = 4 * t;
        orow[PAD + d0 + 0] = acc0;                    // d0 <= 360 always valid
        if (d0 + 1 < ND) orow[PAD + d0 + 1] = acc1;
        if (d0 + 2 < ND) orow[PAD + d0 + 2] = acc2;
        if (d0 + 3 < ND) orow[PAD + d0 + 3] = acc3;
    }
    // zero pads: [0,PAD) and [PAD+ND, ST)
    for (int i = t; i < PAD; i += 128) orow[i] = 0.f;
    for (int i = t; i < ST - (PAD + ND); i += 128) orow[PAD + ND + i] = 0.f;
}

// ---------------------------------------------------------------------------
// Kernel 2: backprojection (unchanged from R5 — ~6-7 us, VALU/TA-bound).
//  - 2048 blocks x 256 threads; wave w handles angles [w*90, w*90+90).
//  - zero-padded filt rows -> branchless float2 bilinear gather.
//  - 4 wave-partials combined in LDS, one coalesced 64-wide store.
// ---------------------------------------------------------------------------
__global__ __launch_bounds__(256, 8) void fbp_backproj(const float* __restrict__ filt,
                                                       float* __restrict__ out,
                                                       float K, float U0p) {
    __shared__ float2 tab[NA];         // (cos*K, sin*K)
    __shared__ float  part[256];
    const int t = threadIdx.x;
    for (int a = t; a < NA; a += 256) {
        float ang = (float)M_PI * (float)a / (float)NA;
        float s, c;
        sincosf(ang, &s, &c);
        tab[a] = make_float2(c * K, s * K);
    }
    __syncthreads();

    const int blk  = blockIdx.x;             // [0, 2048)
    const int img  = blk >> 10;              // {0,1}
    const int iy   = (blk >> 2) & 255;       // [0,256)
    const int jx0  = (blk & 3) * 64;         // pixel segment base
    const int lane = t & 63;                 // pixel within segment
    const int wv   = t >> 6;                 // angle chunk [0,4)

    const float xg = -1.f + 2.f * (float)(jx0 + lane) / 255.f;
    const float yg = -1.f + 2.f * (float)iy / 255.f;

    const float* __restrict__ base = filt + (size_t)img * NA * ST;
    float acc = 0.f;
    const int a0 = wv * (NA / 4);            // 90 angles per wave

#pragma unroll 6
    for (int a = a0; a < a0 + NA / 4; ++a) {
        float2 cs = tab[a];
        float u  = fmaf(xg, cs.x, fmaf(yg, cs.y, U0p));
        float uf = floorf(u);                  // u >= 0 always (padded)
        int   i0 = (int)uf;
        float w  = u - uf;
        const float* rowp = base + a * ST;     // wave-uniform -> saddr form
        float2 tp = *(const float2*)(rowp + i0);  // one dwordx2 gather
        acc = fmaf(w, tp.y - tp.x, acc + tp.x);
    }

    part[t] = acc;
    __syncthreads();

    if (t < 64) {
        float s = part[t] + part[t + 64] + part[t + 128] + part[t + 192];
        out[img * 65536 + iy * 256 + jx0 + t] = s * ((float)M_PI / (float)NA);
    }
}

// ---------------------------------------------------------------------------
extern "C" void kernel_launch(void* const* d_in, const int* in_sizes, int n_in,
                              void* d_out, int out_size, void* d_ws, size_t ws_size,
                              hipStream_t stream) {
    const float* sino = (const float*)d_in[0];   // (2,1,360,363) f32
    float* out = (float*)d_out;                  // (2,1,256,256) f32
    float* htg  = (float*)d_ws;                  // 736 floats (16B-aligned)
    float* filt = (float*)d_ws + 768;            // 720 * 544 floats = 1.57 MB

    // geometry constants (double, matches reference)
    const double scale = (double)(IMG - 1) / 2.0 * sqrt(2.0) / ((double)(ND - 1) / 2.0);
    const float  K   = (float)(0.5 * (double)(ND - 1) / scale);
    const float  U0p = 0.5f * (float)(ND - 1) + (float)PAD;

    fbp_ht<<<2, 368, 0, stream>>>(htg);
    fbp_conv<<<NB * NA, 128, 0, stream>>>(sino, htg, filt);
    fbp_backproj<<<2048, 256, 0, stream>>>(filt, out, K, U0p);
}

// Round 7
// 87.281 us; speedup vs baseline: 1.0558x; 1.0558x over previous
//
#include <hip/hip_runtime.h>
#include <math.h>

#define IMG 256
#define NA  360
#define ND  363
#define NB  2                  // B*C image count
#define KMAX 181               // (ND-1)/2
#define ST  544                // padded row stride for filtered sinogram
#define PAD 76                 // left zero-pad (min u = 181 - 181.7*sqrt(2) > -76)
// reachable padded index range: [0, 514] < ST  (i0 in [-76,437], i1 <= 438)

// ---------------------------------------------------------------------------
// Kernel 1: ramp filter (circular conv) + zero-padded output layout.
// h table per block, f32 with EXACT integer range reduction (no f64):
//   h[n] = S * 4/ND^2,  S = (182*cos(2pi*181n/ND) - 181*cos(2pi*182n/ND) - 1)
//                           / (4*sin^2(pi*n/ND)),   S(0) = 181*182/2
//   cos(2pi*k*n/ND) == cospif(2*((k*|n|) mod ND)/ND)  -- exact reduction,
//   so all trig args are in [0,2]: f32 error ~1e-7, h error ~3e-6.
// Conv loop pairs m,m-1: per-thread tap addresses ht[x], ht[x+1] adjacent ->
// backend merges into ONE ds_read2_b32 (halves LDS issue count, the
// bottleneck). Dual accumulators for fma ILP. srow[m] wave-uniform -> scalar.
// ---------------------------------------------------------------------------
__global__ __launch_bounds__(384) void fbp_conv(const float* __restrict__ sino,
                                                float* __restrict__ filt) {
    __shared__ float ht[2 * ND - 1];   // ht[i] = h_circ[i - 362], i in [0,725)
    const int row = blockIdx.x;
    const int t = threadIdx.x;

    for (int i = t; i < 2 * ND - 1; i += 384) {
        int n  = i - (ND - 1);
        int an = n < 0 ? -n : n;
        float v;
        if (an == 0) {
            v = (float)(KMAX * (KMAX + 1) / 2);          // 16471
        } else {
            int m1 = (KMAX * an) % ND;                    // 181*|n| mod 363
            int m2 = ((KMAX + 1) * an) % ND;              // 182*|n| mod 363
            float c1 = cospif(2.f * (float)m1 / (float)ND);
            float c2 = cospif(2.f * (float)m2 / (float)ND);
            float s  = sinpif((float)an / (float)ND);
            v = (182.f * c1 - 181.f * c2 - 1.f) / (4.f * s * s);
        }
        ht[i] = v * (4.f / ((float)ND * (float)ND));
    }
    __syncthreads();

    const float* __restrict__ srow = sino + (size_t)row * ND;
    float* __restrict__ orow = filt + (size_t)row * ST;

    if (t < ND) {
        float acc0 = 0.f, acc1 = 0.f;
        int x = t;                      // tap index for current m (ascending)
#pragma unroll 8
        for (int m = ND - 1; m >= 1; m -= 2) {
            float h0 = ht[x];
            float h1 = ht[x + 1];       // adjacent -> ds_read2_b32 with h0
            acc0 = fmaf(srow[m],     h0, acc0);
            acc1 = fmaf(srow[m - 1], h1, acc1);
            x += 2;
        }
        // leftover m = 0 (363 taps total)
        acc0 = fmaf(srow[0], ht[t + (ND - 1)], acc0 + acc1);
        orow[PAD + t] = acc0;
    }
    // zero pads: [0,PAD) and [PAD+ND, ST)
    if (t < PAD) orow[t] = 0.f;
    if (t >= PAD && t < PAD + (ST - PAD - ND)) orow[PAD + ND + (t - PAD)] = 0.f;
}

// ---------------------------------------------------------------------------
// Kernel 2: backprojection.
//  - 2048 blocks x 256 threads; wave w (= t>>6) handles angles [w*90,+90).
//  - tab[a] = (cos*K, fma(yg, sin*K, U0p)): the y/offset part is block-
//    uniform, folded into the table -> one fma per angle per thread saved.
//  - zero-padded filt rows -> branchless single float2 bilinear gather.
//  - 4 wave-partials combined in LDS, one coalesced 64-wide store.
//  - __launch_bounds__(256,8): 8 blocks/CU = full 32 waves/CU occupancy.
// ---------------------------------------------------------------------------
__global__ __launch_bounds__(256, 8) void fbp_backproj(const float* __restrict__ filt,
                                                       float* __restrict__ out,
                                                       float K, float U0p) {
    __shared__ float2 tab[NA];         // (cos*K, yg*sin*K + U0p)
    __shared__ float  part[256];
    const int t = threadIdx.x;

    const int blk  = blockIdx.x;             // [0, 2048)
    const int img  = blk >> 10;              // {0,1}
    const int iy   = (blk >> 2) & 255;       // [0,256)
    const int jx0  = (blk & 3) * 64;         // pixel segment base
    const int lane = t & 63;                 // pixel within segment
    const int wv   = t >> 6;                 // angle chunk [0,4)

    const float xg = -1.f + 2.f * (float)(jx0 + lane) / 255.f;
    const float yg = -1.f + 2.f * (float)iy / 255.f;   // block-uniform

    for (int a = t; a < NA; a += 256) {
        float ang = (float)M_PI * (float)a / (float)NA;
        float s, c;
        sincosf(ang, &s, &c);
        tab[a] = make_float2(c * K, fmaf(yg, s * K, U0p));
    }
    __syncthreads();

    const float* __restrict__ base = filt + (size_t)img * NA * ST;
    float acc = 0.f;
    const int a0 = wv * (NA / 4);            // 90 angles per wave

#pragma unroll 6
    for (int a = a0; a < a0 + NA / 4; ++a) {
        float2 cs = tab[a];
        float u  = fmaf(xg, cs.x, cs.y);       // cs.y = yg*sK + U0p
        float uf = floorf(u);                  // u >= 0 always (padded)
        int   i0 = (int)uf;
        float w  = u - uf;
        const float* rowp = base + a * ST;     // wave-uniform -> saddr form
        float2 tp = *(const float2*)(rowp + i0);  // one dwordx2 gather
        acc = fmaf(w, tp.y - tp.x, acc + tp.x);
    }

    part[t] = acc;
    __syncthreads();

    if (t < 64) {
        float s = part[t] + part[t + 64] + part[t + 128] + part[t + 192];
        out[img * 65536 + iy * 256 + jx0 + t] = s * ((float)M_PI / (float)NA);
    }
}

// ---------------------------------------------------------------------------
extern "C" void kernel_launch(void* const* d_in, const int* in_sizes, int n_in,
                              void* d_out, int out_size, void* d_ws, size_t ws_size,
                              hipStream_t stream) {
    const float* sino = (const float*)d_in[0];   // (2,1,360,363) f32
    float* out = (float*)d_out;                  // (2,1,256,256) f32
    float* filt = (float*)d_ws;                  // 720 * 544 floats = 1.57 MB

    // geometry constants (double, matches reference)
    const double scale = (double)(IMG - 1) / 2.0 * sqrt(2.0) / ((double)(ND - 1) / 2.0);
    const float  K   = (float)(0.5 * (double)(ND - 1) / scale);
    const float  U0p = 0.5f * (float)(ND - 1) + (float)PAD;

    fbp_conv<<<NB * NA, 384, 0, stream>>>(sino, filt);
    fbp_backproj<<<2048, 256, 0, stream>>>(filt, out, K, U0p);
}

// Round 8
// 85.787 us; speedup vs baseline: 1.0741x; 1.0174x over previous
//
#include <hip/hip_runtime.h>
#include <math.h>

#define IMG 256
#define NA  360
#define ND  363
#define NB  2                  // B*C image count
#define KMAX 181               // (ND-1)/2
#define ST  544                // padded row stride for filtered sinogram
#define PAD 76                 // left zero-pad (min u = 181 - 181.7*sqrt(2) > -76)
// reachable padded index range: [0, 514] < ST  (i0 in [-76,437], i1 <= 438)

// ---------------------------------------------------------------------------
// Kernel 1: ramp filter (circular conv), 2 outputs/thread, 2 rows/block.
// h table (726 floats; [725]=0 pad) built in f32 with EXACT integer range
// reduction:  h[n] = S*4/ND^2,
//   S = (182*cos(2pi*(181|n| mod ND)/ND) - 181*cos(2pi*(182|n| mod ND)/ND) - 1)
//       / (4*sin^2(pi*|n|/ND)),  S(0)=181*182/2.
// Thread computes outputs d0=2*tt, d0+1 for its row. Per 4-m chunk the two
// outputs' taps are the contiguous window ht[x..x+4] (x=2*tt+4c, even):
// 2 new ds_read_b64 per 8 FMAs — HALF the LDS bytes/issues per output of the
// R7 ds_read2 scheme (the measured bottleneck). p2 is carried into the next
// chunk's p0. srow[m] is wave-uniform -> scalar loads. 360 blocks x 6 waves
// = 2160 waves (~8.4 waves/CU): enough TLP for the LDS pipe.
// ---------------------------------------------------------------------------
__global__ __launch_bounds__(384) void fbp_conv(const float* __restrict__ sino,
                                                float* __restrict__ filt) {
    __shared__ float ht[726];          // ht[i] = h_circ[i - 362], i in [0,725); [725]=0
    const int t = threadIdx.x;

    for (int i = t; i < 726; i += 384) {
        float v = 0.f;
        if (i <= 724) {
            int n  = i - 362;
            int an = n < 0 ? -n : n;
            if (an == 0) {
                v = (float)(KMAX * (KMAX + 1) / 2);      // 16471
            } else {
                int m1 = (KMAX * an) % ND;                // 181*|n| mod 363
                int m2 = ((KMAX + 1) * an) % ND;          // 182*|n| mod 363
                float c1 = cospif(2.f * (float)m1 / (float)ND);
                float c2 = cospif(2.f * (float)m2 / (float)ND);
                float s  = sinpif((float)an / (float)ND);
                v = (182.f * c1 - 181.f * c2 - 1.f) / (4.f * s * s);
            }
            v *= 4.f / ((float)ND * (float)ND);
        }
        ht[i] = v;
    }
    __syncthreads();

    const int r   = t / 192;                 // row half {0,1} (3 whole waves each)
    const int tt  = t - r * 192;             // [0,192)
    const int row = 2 * blockIdx.x + r;
    const float* __restrict__ srow = sino + (size_t)row * ND;
    float* __restrict__ orow = filt + (size_t)row * ST;

    if (tt < 182) {
        const float2* ht2 = (const float2*)ht;
        float acc0 = 0.f, acc1 = 0.f;
        float2 p0 = ht2[tt];                 // window base x = 2*tt
#pragma unroll 5
        for (int c = 0; c < 90; ++c) {
            float2 p1 = ht2[tt + 2 * c + 1];
            float2 p2 = ht2[tt + 2 * c + 2];
            float s0 = srow[362 - 4 * c];    // wave-uniform scalar loads
            float s1 = srow[361 - 4 * c];
            float s2 = srow[360 - 4 * c];
            float s3 = srow[359 - 4 * c];
            acc0 = fmaf(s0, p0.x, acc0);  acc1 = fmaf(s0, p0.y, acc1);
            acc0 = fmaf(s1, p0.y, acc0);  acc1 = fmaf(s1, p1.x, acc1);
            acc0 = fmaf(s2, p1.x, acc0);  acc1 = fmaf(s2, p1.y, acc1);
            acc0 = fmaf(s3, p1.y, acc0);  acc1 = fmaf(s3, p2.x, acc1);
            p0 = p2;                          // reuse as next chunk's base pair
        }
        // tail m = 2,1,0: window x = 2*tt+360 -> p0 (carried) + one more pair
        {
            float2 q1 = ht2[tt + 181];        // (x+2, x+3); x+3 <= 725 (pad)
            float s2m = srow[2], s1m = srow[1], s0m = srow[0];
            acc0 = fmaf(s2m, p0.x, acc0);  acc1 = fmaf(s2m, p0.y, acc1);
            acc0 = fmaf(s1m, p0.y, acc0);  acc1 = fmaf(s1m, q1.x, acc1);
            acc0 = fmaf(s0m, q1.x, acc0);  acc1 = fmaf(s0m, q1.y, acc1);
        }
        if (tt < 181) {
            *(float2*)(orow + PAD + 2 * tt) = make_float2(acc0, acc1);
        } else {
            orow[PAD + 362] = acc0;           // d=363 doesn't exist
        }
    }
    // zero pads per row: [0,PAD) and [PAD+ND, ST)
    for (int i = tt; i < PAD; i += 192) orow[i] = 0.f;
    for (int i = tt; i < ST - (PAD + ND); i += 192) orow[PAD + ND + i] = 0.f;
}

// ---------------------------------------------------------------------------
// Kernel 2: backprojection.
//  - 2048 blocks x 256 threads; wave wv handles angles [wv*90, wv*90+90).
//  - tab4[p] = (cK[2p], yg*sK[2p]+U0p, cK[2p+1], yg*sK[2p+1]+U0p): y-part is
//    block-uniform (folded); ONE float4 LDS read feeds TWO angles.
//  - zero-padded filt rows -> branchless single float2 bilinear gather.
//  - 4 wave-partials combined in LDS, one coalesced 64-wide store.
//  - __launch_bounds__(256,8): 8 blocks/CU = full 32 waves/CU occupancy.
// ---------------------------------------------------------------------------
__global__ __launch_bounds__(256, 8) void fbp_backproj(const float* __restrict__ filt,
                                                       float* __restrict__ out,
                                                       float K, float U0p) {
    __shared__ float4 tab4[NA / 2];    // angle pairs
    __shared__ float  part[256];
    const int t = threadIdx.x;

    const int blk  = blockIdx.x;             // [0, 2048)
    const int img  = blk >> 10;              // {0,1}
    const int iy   = (blk >> 2) & 255;       // [0,256)
    const int jx0  = (blk & 3) * 64;         // pixel segment base
    const int lane = t & 63;                 // pixel within segment
    const int wv   = t >> 6;                 // angle chunk [0,4)

    const float xg = -1.f + 2.f * (float)(jx0 + lane) / 255.f;
    const float yg = -1.f + 2.f * (float)iy / 255.f;   // block-uniform

    for (int p = t; p < NA / 2; p += 256) {
        float a0 = (float)M_PI * (float)(2 * p)     / (float)NA;
        float a1 = (float)M_PI * (float)(2 * p + 1) / (float)NA;
        float s0, c0, s1, c1;
        sincosf(a0, &s0, &c0);
        sincosf(a1, &s1, &c1);
        tab4[p] = make_float4(c0 * K, fmaf(yg, s0 * K, U0p),
                              c1 * K, fmaf(yg, s1 * K, U0p));
    }
    __syncthreads();

    const float* __restrict__ base = filt + (size_t)img * NA * ST;
    float acc = 0.f;
    const int p0 = wv * 45;                  // 90 angles = 45 pairs per wave

#pragma unroll 5
    for (int p = p0; p < p0 + 45; ++p) {
        float4 cy = tab4[p];
        const float* rowp = base + (2 * p) * ST;   // wave-uniform -> saddr
        // angle 2p
        float u  = fmaf(xg, cy.x, cy.y);
        float uf = floorf(u);                      // u >= 0 always (padded)
        int   i0 = (int)uf;
        float w  = u - uf;
        float2 tp = *(const float2*)(rowp + i0);
        acc = fmaf(w, tp.y - tp.x, acc + tp.x);
        // angle 2p+1
        float u2  = fmaf(xg, cy.z, cy.w);
        float uf2 = floorf(u2);
        int   i2  = (int)uf2;
        float w2  = u2 - uf2;
        float2 tq = *(const float2*)(rowp + ST + i2);
        acc = fmaf(w2, tq.y - tq.x, acc + tq.x);
    }

    part[t] = acc;
    __syncthreads();

    if (t < 64) {
        float s = part[t] + part[t + 64] + part[t + 128] + part[t + 192];
        out[img * 65536 + iy * 256 + jx0 + t] = s * ((float)M_PI / (float)NA);
    }
}

// ---------------------------------------------------------------------------
extern "C" void kernel_launch(void* const* d_in, const int* in_sizes, int n_in,
                              void* d_out, int out_size, void* d_ws, size_t ws_size,
                              hipStream_t stream) {
    const float* sino = (const float*)d_in[0];   // (2,1,360,363) f32
    float* out = (float*)d_out;                  // (2,1,256,256) f32
    float* filt = (float*)d_ws;                  // 720 * 544 floats = 1.57 MB

    // geometry constants (double, matches reference)
    const double scale = (double)(IMG - 1) / 2.0 * sqrt(2.0) / ((double)(ND - 1) / 2.0);
    const float  K   = (float)(0.5 * (double)(ND - 1) / scale);
    const float  U0p = 0.5f * (float)(ND - 1) + (float)PAD;

    fbp_conv<<<NB * NA / 2, 384, 0, stream>>>(sino, filt);
    fbp_backproj<<<2048, 256, 0, stream>>>(filt, out, K, U0p);
}